// Round 4
// baseline (155.161 us; speedup 1.0000x reference)
//
#include <hip/hip_runtime.h>
#include <cstdint>
#include <cstddef>

using short8 = __attribute__((ext_vector_type(8))) short;   // 8 bf16 (4 VGPRs)
using f32x4  = __attribute__((ext_vector_type(4))) float;   // MFMA C/D 16x16
using f32x16 = __attribute__((ext_vector_type(16))) float;  // MFMA C/D 32x32
using u32x4  = __attribute__((ext_vector_type(4))) unsigned int;

#define DEV static __device__ __forceinline__

constexpr int Bn = 4, Cn = 256, Ln = 2048, Hn = 8, Dn = 64, HIDn = 512;

DEV unsigned short f2bf(float f){            // fp32 -> bf16 bits, round-nearest-even
  union { float f; uint32_t u; } v; v.f = f;
  uint32_t u = v.u;
  return (unsigned short)((u + 0x7FFFu + ((u >> 16) & 1u)) >> 16);
}

DEV uint32_t cvtpk(float lo, float hi){      // pack 2 f32 -> 2 bf16 (lo -> bits[15:0])
  uint32_t r;
  asm("v_cvt_pk_bf16_f32 %0, %1, %2" : "=v"(r) : "v"(lo), "v"(hi));
  return r;
}

DEV float fmax3(float a, float b, float c){ return fmaxf(fmaxf(a, b), c); }  // fuses to v_max3_f32

// async global -> LDS, 16B per lane, linear dest (wave-uniform base + lane*16)
DEV void gl16(const unsigned short* g, unsigned short* l){
  __builtin_amdgcn_global_load_lds((const __attribute__((address_space(1))) void*)g,
                                   (__attribute__((address_space(3))) void*)l, 16, 0, 0);
}

// ---------------- f32 -> bf16 weight convert ----------------
__global__ __launch_bounds__(256) void k_cvt(const float* __restrict__ in,
                                             unsigned short* __restrict__ out, int n){
  int i = blockIdx.x * 256 + threadIdx.x;
  int stride = gridDim.x * 256;
  for (; i < n; i += stride) out[i] = f2bf(in[i]);
}

// ---------------- column norms: s[b*Ln+l] = sqrt(Cn)/max(||x[:,l]||, eps) ----------------
__global__ __launch_bounds__(256) void k_colnorm(const float* __restrict__ x,
                                                 float* __restrict__ s){
  __shared__ float ps[4][64];
  int gcol = blockIdx.x * 64;
  int b = gcol >> 11;
  int l = (gcol & 2047) + (threadIdx.x & 63);
  int w = threadIdx.x >> 6;
  const float* xp = x + ((size_t)b * Cn + w * 64) * Ln + l;
  float acc = 0.f;
  #pragma unroll 8
  for (int cc = 0; cc < 64; ++cc){ float v = xp[(size_t)cc * Ln]; acc += v * v; }
  ps[w][threadIdx.x & 63] = acc;
  __syncthreads();
  if (threadIdx.x < 64){
    float t = ps[0][threadIdx.x] + ps[1][threadIdx.x] + ps[2][threadIdx.x] + ps[3][threadIdx.x];
    s[gcol + threadIdx.x] = 16.0f / fmaxf(sqrtf(t), 1e-12f);
  }
}

// ---------------- transpose + scale + g1 + bf16: xT[(b*Ln+l)*Cn + c] ----------------
__global__ __launch_bounds__(256) void k_xt(const float* __restrict__ x,
                                            const float* __restrict__ s,
                                            const float* __restrict__ g1,
                                            unsigned short* __restrict__ xT){
  __shared__ float xs[64][65];
  int b  = blockIdx.z;
  int c0 = blockIdx.y * 64;
  int l0 = blockIdx.x * 64;
  int t  = threadIdx.x;
  int i = t >> 6, j = t & 63;
  const float* xp = x + ((size_t)b * Cn + c0) * Ln + l0;
  #pragma unroll
  for (int it = 0; it < 16; ++it)
    xs[i + it * 4][j] = xp[(size_t)(i + it * 4) * Ln + j];
  __syncthreads();
  int jj = t >> 2, part = t & 3;
  float sc = s[b * Ln + l0 + jj];
  unsigned short* op = xT + ((size_t)(b * Ln + l0 + jj)) * Cn + c0 + part * 16;
  #pragma unroll
  for (int hb = 0; hb < 2; ++hb){
    short8 pack;
    #pragma unroll
    for (int m = 0; m < 8; ++m){
      int c = part * 16 + hb * 8 + m;
      pack[m] = (short)f2bf(xs[c][jj] * sc * g1[c0 + c]);
    }
    *reinterpret_cast<short8*>(op + hb * 8) = pack;
  }
}

// ---------------- QK GEMM, D[l][o] orientation -> q,k in (b,h,l,d) bf16 ----------------
__global__ __launch_bounds__(256) void k_gemm_qk(const unsigned short* __restrict__ xT,
                                                 const unsigned short* __restrict__ w,
                                                 unsigned short* __restrict__ qb,
                                                 unsigned short* __restrict__ kb){
  int b  = blockIdx.z;
  int l0 = blockIdx.x * 128;
  int n0 = blockIdx.y * 64;
  int wv = threadIdx.x >> 6, lane = threadIdx.x & 63;
  int grp = lane >> 4, lc = lane & 15;
  int lw = l0 + (wv >> 1) * 64;
  int nw = n0 + (wv & 1) * 32;
  f32x4 acc[4][2] = {};
  const unsigned short* xb = xT + (size_t)b * Ln * Cn;
  for (int k0 = 0; k0 < Cn; k0 += 32){
    int kc = k0 + grp * 8;
    short8 afr[4], bfr[2];
    #pragma unroll
    for (int mt = 0; mt < 4; ++mt)
      afr[mt] = *reinterpret_cast<const short8*>(xb + (size_t)(lw + mt * 16 + lc) * Cn + kc);
    #pragma unroll
    for (int nt = 0; nt < 2; ++nt)
      bfr[nt] = *reinterpret_cast<const short8*>(w + (size_t)(nw + nt * 16 + lc) * Cn + kc);
    #pragma unroll
    for (int mt = 0; mt < 4; ++mt)
      #pragma unroll
      for (int nt = 0; nt < 2; ++nt)
        acc[mt][nt] = __builtin_amdgcn_mfma_f32_16x16x32_bf16(afr[mt], bfr[nt], acc[mt][nt], 0, 0, 0);
  }
  // q scale folds dim_head^-0.5 AND log2(e) (attn softmax runs in exp2 domain)
  const float QSCALE = 0.125f * 1.4426950408889634f;
  #pragma unroll
  for (int mt = 0; mt < 4; ++mt)
    #pragma unroll
    for (int nt = 0; nt < 2; ++nt)
      #pragma unroll
      for (int r = 0; r < 4; ++r){
        int l = lw + mt * 16 + grp * 4 + r;
        int o = nw + nt * 16 + lc;
        float v = acc[mt][nt][r];
        if (o < HIDn){
          size_t idx = (((size_t)(b * Hn + (o >> 6)) * Ln + l) << 6) | (size_t)(o & 63);
          qb[idx] = f2bf(v * QSCALE);
        } else {
          int o2 = o - HIDn;
          size_t idx = (((size_t)(b * Hn + (o2 >> 6)) * Ln + l) << 6) | (size_t)(o2 & 63);
          kb[idx] = f2bf(v);
        }
      }
}

// ---------------- V GEMM, D[o][l] orientation -> v in (b, 512, l) bf16 ----------------
__global__ __launch_bounds__(256) void k_gemm_v(const unsigned short* __restrict__ xT,
                                                const unsigned short* __restrict__ w,
                                                unsigned short* __restrict__ vb){
  int b  = blockIdx.z;
  int m0 = blockIdx.y * 64;
  int l0 = blockIdx.x * 128;
  int wv = threadIdx.x >> 6, lane = threadIdx.x & 63;
  int grp = lane >> 4, lc = lane & 15;
  int mw = m0 + (wv >> 1) * 32;
  int lw = l0 + (wv & 1) * 64;
  f32x4 acc[2][4] = {};
  const unsigned short* xb = xT + (size_t)b * Ln * Cn;
  const unsigned short* wvp = w + (size_t)1024 * Cn;
  for (int k0 = 0; k0 < Cn; k0 += 32){
    int kc = k0 + grp * 8;
    short8 afr[2], bfr[4];
    #pragma unroll
    for (int mt = 0; mt < 2; ++mt)
      afr[mt] = *reinterpret_cast<const short8*>(wvp + (size_t)(mw + mt * 16 + lc) * Cn + kc);
    #pragma unroll
    for (int nt = 0; nt < 4; ++nt)
      bfr[nt] = *reinterpret_cast<const short8*>(xb + (size_t)(lw + nt * 16 + lc) * Cn + kc);
    #pragma unroll
    for (int mt = 0; mt < 2; ++mt)
      #pragma unroll
      for (int nt = 0; nt < 4; ++nt)
        acc[mt][nt] = __builtin_amdgcn_mfma_f32_16x16x32_bf16(afr[mt], bfr[nt], acc[mt][nt], 0, 0, 0);
  }
  #pragma unroll
  for (int mt = 0; mt < 2; ++mt)
    #pragma unroll
    for (int nt = 0; nt < 4; ++nt)
      #pragma unroll
      for (int r = 0; r < 4; ++r){
        int o = mw + mt * 16 + grp * 4 + r;
        int l = lw + nt * 16 + lc;
        vb[((size_t)(b * HIDn + o)) * Ln + l] = f2bf(acc[mt][nt][r]);
      }
}

// ---------------- flash attention, swapped-operand 32x32 structure ----------------
// 512 blocks (XCD-swizzled) x 4 waves; wave owns 32 q-rows; KVBLK=64, dbuf LDS.
// Staging via global_load_lds (linear dest, pre-swizzled per-lane source), 1 barrier/tile.
// S^T = mfma(K,Q) -> lane-local softmax. Cross-half moves via PROVEN shfl_xor(32)
// (permlane32_swap builtin reverted: unverified return convention caused R3 fail).
// Defer-max (T13, THR=8 in exp2 domain) skips the O-rescale on stable tiles.
__global__ __launch_bounds__(256) void k_attn(const unsigned short* __restrict__ qb,
                                              const unsigned short* __restrict__ kb,
                                              const unsigned short* __restrict__ vb,
                                              unsigned short* __restrict__ yb){
  int wid = (blockIdx.x & 7) * 64 + (blockIdx.x >> 3);   // XCD-aware, bijective (512 % 8 == 0)
  int qt = wid & 15;
  int bh = wid >> 4;
  int b = bh >> 3, h = bh & 7;
  int tid = threadIdx.x;
  int wv = tid >> 6, lane = tid & 63;
  int ln = lane & 31, hi = lane >> 5;

  const unsigned short* qp = qb + (size_t)bh * Ln * Dn;
  const unsigned short* kp = kb + (size_t)bh * Ln * Dn;
  const unsigned short* vp = vb + ((size_t)(b * HIDn + h * Dn)) * Ln;
  unsigned short* yp = yb + (size_t)b * Ln * HIDn + h * Dn;

  __shared__ alignas(16) unsigned short KV[2][2][4096];   // [buf][K|V][64 rows x 64], XOR-swizzled content

  // staging: wave wv owns rows [wv*16, wv*16+16), 2 gl16 per operand (8 rows each).
  // LDS dest is linear; source global addr pre-swizzled: chunk = lcol ^ (row & 7).
  int lrow = lane >> 3, lcol = lane & 7;
  int chunk = lcol ^ lrow;                      // row & 7 == lrow for both 8-row instrs
  int srow = wv * 16 + lrow;
  const unsigned short* kg = kp + (size_t)srow * Dn + chunk * 8;
  const unsigned short* vg = vp + (size_t)srow * Ln + chunk * 8;
  int ldK = wv * 1024;                          // element offset of this wave's 16 rows

  int q = qt * 128 + wv * 32 + ln;
  short8 qfr[4];
  #pragma unroll
  for (int s = 0; s < 4; ++s)
    qfr[s] = *reinterpret_cast<const short8*>(qp + (size_t)q * Dn + s * 16 + hi * 8);

  f32x16 accO[2] = {};
  float m = -1e30f, lsum = 0.f;

  // prologue: tile 0 -> buf 0 (async DMA)
  gl16(kg,            &KV[0][0][ldK]);
  gl16(kg + 8 * Dn,   &KV[0][0][ldK + 512]);
  gl16(vg,            &KV[0][1][ldK]);
  gl16(vg + 8 * Ln,   &KV[0][1][ldK + 512]);

  int sw = (ln & 7) << 4;

  for (int t = 0; t < 32; ++t){
    asm volatile("s_waitcnt vmcnt(0)");
    __syncthreads();

    // issue next tile's DMA immediately (has the whole tile's compute to land)
    if (t + 1 < 32){
      const unsigned short* kgn = kg + (size_t)(t + 1) * 64 * Dn;
      const unsigned short* vgn = vg + (size_t)(t + 1) * 64;
      unsigned short* Kd = &KV[(t + 1) & 1][0][ldK];
      unsigned short* Vd = &KV[(t + 1) & 1][1][ldK];
      gl16(kgn,          Kd);
      gl16(kgn + 8 * Dn, Kd + 512);
      gl16(vgn,          Vd);
      gl16(vgn + 8 * Ln, Vd + 512);
    }
    const char* Kc = (const char*)&KV[t & 1][0][0];
    const char* Vc = (const char*)&KV[t & 1][1][0];

    // ---- S^T = K Q^T : sacc[kb2] covers keys j = kb2*32 + crow(r,hi), col q = ln
    f32x16 sacc[2] = {};
    __builtin_amdgcn_s_setprio(1);
    #pragma unroll
    for (int kb2 = 0; kb2 < 2; ++kb2){
      const char* Kr = Kc + (kb2 * 32 + ln) * 128;
      #pragma unroll
      for (int s = 0; s < 4; ++s){
        short8 kf = *reinterpret_cast<const short8*>(Kr + ((s * 32 + hi * 16) ^ sw));
        sacc[kb2] = __builtin_amdgcn_mfma_f32_32x32x16_bf16(kf, qfr[s], sacc[kb2], 0, 0, 0);
      }
    }
    __builtin_amdgcn_s_setprio(0);

    // ---- tile max (max3 tree + one cross-half shfl)
    float mx[16];
    #pragma unroll
    for (int r = 0; r < 16; ++r) mx[r] = fmaxf(sacc[0][r], sacc[1][r]);
    float t0 = fmax3(mx[0], mx[1], mx[2]);
    float t1 = fmax3(mx[3], mx[4], mx[5]);
    float t2 = fmax3(mx[6], mx[7], mx[8]);
    float t3 = fmax3(mx[9], mx[10], mx[11]);
    float t4 = fmax3(mx[12], mx[13], mx[14]);
    float pl = fmaxf(fmax3(t0, t1, t2), fmax3(t3, t4, mx[15]));
    float pmax = fmaxf(pl, __shfl_xor(pl, 32, 64));

    // ---- defer-max: only rescale when the running max grew by > 8 (exp2 domain)
    if (!__all(pmax - m <= 8.0f)){
      float mn = fmaxf(m, pmax);
      float corr = exp2f(m - mn);
      lsum *= corr;
      #pragma unroll
      for (int db = 0; db < 2; ++db)
        #pragma unroll
        for (int r = 0; r < 16; ++r) accO[db][r] *= corr;
      m = mn;
    }

    // ---- P = exp2(S - m); per-lane partial sums
    float s0[16];
    #pragma unroll
    for (int r = 0; r < 16; ++r){
      float p0 = exp2f(sacc[0][r] - m); sacc[0][r] = p0;
      float p1 = exp2f(sacc[1][r] - m); sacc[1][r] = p1;
      s0[r] = p0 + p1;
    }
    #pragma unroll
    for (int st = 8; st >= 1; st >>= 1)
      #pragma unroll
      for (int r = 0; r < st; ++r) s0[r] += s0[r + st];
    lsum += s0[0] + __shfl_xor(s0[0], 32, 64);

    // ---- P (D-layout) -> P^T B-frags: cvt_pk + shfl_xor(32) + select (R2-proven)
    u32x4 W[4];
    #pragma unroll
    for (int kb2 = 0; kb2 < 2; ++kb2)
      #pragma unroll
      for (int sl = 0; sl < 2; ++sl){
        int bse = sl * 8;
        uint32_t a0 = cvtpk(sacc[kb2][bse + 0], sacc[kb2][bse + 1]);
        uint32_t a1 = cvtpk(sacc[kb2][bse + 2], sacc[kb2][bse + 3]);
        uint32_t b0 = cvtpk(sacc[kb2][bse + 4], sacc[kb2][bse + 5]);
        uint32_t b1 = cvtpk(sacc[kb2][bse + 6], sacc[kb2][bse + 7]);
        uint32_t xb0 = __shfl_xor(b0, 32, 64);
        uint32_t xb1 = __shfl_xor(b1, 32, 64);
        uint32_t xa0 = __shfl_xor(a0, 32, 64);
        uint32_t xa1 = __shfl_xor(a1, 32, 64);
        int ks = kb2 * 2 + sl;
        W[ks][0] = hi ? xb0 : a0;
        W[ks][1] = hi ? xb1 : a1;
        W[ks][2] = hi ? b0  : xa0;
        W[ks][3] = hi ? b1  : xa1;
      }

    // ---- O^T += V^T P^T
    __builtin_amdgcn_s_setprio(1);
    #pragma unroll
    for (int db = 0; db < 2; ++db){
      const char* Vr = Vc + (db * 32 + ln) * 128;
      #pragma unroll
      for (int ks = 0; ks < 4; ++ks){
        short8 vf = *reinterpret_cast<const short8*>(Vr + ((ks * 32 + hi * 16) ^ sw));
        accO[db] = __builtin_amdgcn_mfma_f32_32x32x16_bf16(vf, __builtin_bit_cast(short8, W[ks]), accO[db], 0, 0, 0);
      }
    }
    __builtin_amdgcn_s_setprio(0);
  }

  // ---- epilogue: O^T[d][q] / lsum -> y[(b,l,512)]
  float inv = 1.0f / lsum;
  #pragma unroll
  for (int db = 0; db < 2; ++db)
    #pragma unroll
    for (int rq = 0; rq < 4; ++rq){
      uint32_t w0 = cvtpk(accO[db][rq * 4 + 0] * inv, accO[db][rq * 4 + 1] * inv);
      uint32_t w1 = cvtpk(accO[db][rq * 4 + 2] * inv, accO[db][rq * 4 + 3] * inv);
      int dd = db * 32 + rq * 8 + hi * 4;
      uint32_t* dst = reinterpret_cast<uint32_t*>(yp + (size_t)q * HIDn + dd);
      dst[0] = w0; dst[1] = w1;
    }
}

// ---------------- out GEMM (M=256 full) + bias + fused RMSNorm + g2 ----------------
__global__ __launch_bounds__(256) void k_out(const unsigned short* __restrict__ yb,
                                             const unsigned short* __restrict__ w,
                                             const float* __restrict__ bias,
                                             const float* __restrict__ g2,
                                             float* __restrict__ out){
  int b  = blockIdx.y;
  int l0 = blockIdx.x * 32;
  int wv = threadIdx.x >> 6, lane = threadIdx.x & 63;
  int grp = lane >> 4, lc = lane & 15;
  int mw = wv * 64;
  f32x4 acc[4][2] = {};
  const unsigned short* ybp = yb + (size_t)b * Ln * HIDn + (size_t)l0 * HIDn;
  for (int k0 = 0; k0 < HIDn; k0 += 32){
    int kc = k0 + grp * 8;
    short8 afr[4], bfr[2];
    #pragma unroll
    for (int mt = 0; mt < 4; ++mt)
      afr[mt] = *reinterpret_cast<const short8*>(w + (size_t)(mw + mt * 16 + lc) * HIDn + kc);
    #pragma unroll
    for (int nt = 0; nt < 2; ++nt)
      bfr[nt] = *reinterpret_cast<const short8*>(ybp + (size_t)(nt * 16 + lc) * HIDn + kc);
    #pragma unroll
    for (int mt = 0; mt < 4; ++mt)
      #pragma unroll
      for (int nt = 0; nt < 2; ++nt)
        acc[mt][nt] = __builtin_amdgcn_mfma_f32_16x16x32_bf16(afr[mt], bfr[nt], acc[mt][nt], 0, 0, 0);
  }
  __shared__ float cs[4][32];
  __shared__ float sc2[32];
  float part[2] = {0.f, 0.f};
  #pragma unroll
  for (int mt = 0; mt < 4; ++mt)
    #pragma unroll
    for (int nt = 0; nt < 2; ++nt)
      #pragma unroll
      for (int r = 0; r < 4; ++r){
        int o = mw + mt * 16 + grp * 4 + r;
        float v = acc[mt][nt][r] + bias[o];
        acc[mt][nt][r] = v;
        part[nt] += v * v;
      }
  #pragma unroll
  for (int nt = 0; nt < 2; ++nt)
    #pragma unroll
    for (int sh = 16; sh < 64; sh <<= 1) part[nt] += __shfl_xor(part[nt], sh, 64);
  if (lane < 16){ cs[wv][lc] = part[0]; cs[wv][16 + lc] = part[1]; }
  __syncthreads();
  if (threadIdx.x < 32){
    float t = cs[0][threadIdx.x] + cs[1][threadIdx.x] + cs[2][threadIdx.x] + cs[3][threadIdx.x];
    sc2[threadIdx.x] = 16.0f / fmaxf(sqrtf(t), 1e-12f);
  }
  __syncthreads();
  #pragma unroll
  for (int nt = 0; nt < 2; ++nt){
    float s2 = sc2[nt * 16 + lc];
    #pragma unroll
    for (int mt = 0; mt < 4; ++mt)
      #pragma unroll
      for (int r = 0; r < 4; ++r){
        int o = mw + mt * 16 + grp * 4 + r;
        int l = l0 + nt * 16 + lc;
        out[((size_t)(b * Cn + o)) * Ln + l] = acc[mt][nt][r] * s2 * g2[o];
      }
  }
}

// ---------------- launch ----------------
extern "C" void kernel_launch(void* const* d_in, const int* in_sizes, int n_in,
                              void* d_out, int out_size, void* d_ws, size_t ws_size,
                              hipStream_t stream){
  const float* x     = (const float*)d_in[0];
  const float* g1    = (const float*)d_in[1];
  const float* w_qkv = (const float*)d_in[2];
  const float* w_out = (const float*)d_in[3];
  const float* b_out = (const float*)d_in[4];
  const float* g2    = (const float*)d_in[5];

  char* wsb = (char*)d_ws;
  unsigned short* wqkv_b = (unsigned short*)(wsb + 0);
  unsigned short* wout_b = (unsigned short*)(wsb + 786432);
  float*          sbuf   = (float*)        (wsb + 1048576);
  unsigned short* xT     = (unsigned short*)(wsb + 1081344);
  unsigned short* qbuf   = (unsigned short*)(wsb + 5275648);
  unsigned short* kbuf   = (unsigned short*)(wsb + 13664256);
  unsigned short* vbuf   = (unsigned short*)(wsb + 22052864);
  unsigned short* ybuf   = (unsigned short*)(wsb + 30441472);

  k_cvt<<<384, 256, 0, stream>>>(w_qkv, wqkv_b, 1536 * 256);
  k_cvt<<<128, 256, 0, stream>>>(w_out, wout_b, 256 * 512);
  k_colnorm<<<128, 256, 0, stream>>>(x, sbuf);
  k_xt<<<dim3(32, 4, 4), 256, 0, stream>>>(x, sbuf, g1, xT);
  k_gemm_qk<<<dim3(16, 16, 4), 256, 0, stream>>>(xT, wqkv_b, qbuf, kbuf);
  k_gemm_v<<<dim3(16, 8, 4), 256, 0, stream>>>(xT, wqkv_b, vbuf);
  k_attn<<<512, 256, 0, stream>>>(qbuf, kbuf, vbuf, ybuf);
  k_out<<<dim3(64, 4), 256, 0, stream>>>(ybuf, wout_b, b_out, g2, (float*)d_out);
}

// Round 6
// 132.519 us; speedup vs baseline: 1.1709x; 1.1709x over previous
//
#include <hip/hip_runtime.h>
#include <cstdint>
#include <cstddef>

using s16x4  = __attribute__((ext_vector_type(4))) short;   // 4 bf16 (2 VGPRs)
using short8 = __attribute__((ext_vector_type(8))) short;   // 8 bf16 (4 VGPRs)
using f32x4  = __attribute__((ext_vector_type(4))) float;   // MFMA C/D 16x16
using f32x16 = __attribute__((ext_vector_type(16))) float;  // MFMA C/D 32x32
using u32x4  = __attribute__((ext_vector_type(4))) unsigned int;

#define DEV static __device__ __forceinline__

constexpr int Bn = 4, Cn = 256, Ln = 2048, Hn = 8, Dn = 64, HIDn = 512;

DEV unsigned short f2bf(float f){            // fp32 -> bf16 bits, round-nearest-even
  union { float f; uint32_t u; } v; v.f = f;
  uint32_t u = v.u;
  return (unsigned short)((u + 0x7FFFu + ((u >> 16) & 1u)) >> 16);
}

DEV uint32_t cvtpk(float lo, float hi){      // pack 2 f32 -> 2 bf16 (lo -> bits[15:0])
  uint32_t r;
  asm("v_cvt_pk_bf16_f32 %0, %1, %2" : "=v"(r) : "v"(lo), "v"(hi));
  return r;
}

DEV float fmax3(float a, float b, float c){ return fmaxf(fmaxf(a, b), c); }  // fuses to v_max3_f32

// async global -> LDS, 16B per lane, linear dest (wave-uniform base + lane*16)
DEV void gl16(const unsigned short* g, unsigned short* l){
  __builtin_amdgcn_global_load_lds((const __attribute__((address_space(1))) void*)g,
                                   (__attribute__((address_space(3))) void*)l, 16, 0, 0);
}

// ---------------- f32 -> bf16 weight convert ----------------
__global__ __launch_bounds__(256) void k_cvt(const float* __restrict__ in,
                                             unsigned short* __restrict__ out, int n){
  int i = blockIdx.x * 256 + threadIdx.x;
  int stride = gridDim.x * 256;
  for (; i < n; i += stride) out[i] = f2bf(in[i]);
}

// ---------------- column norms: s[b*Ln+l] = sqrt(Cn)/max(||x[:,l]||, eps) ----------------
__global__ __launch_bounds__(256) void k_colnorm(const float* __restrict__ x,
                                                 float* __restrict__ s){
  __shared__ float ps[4][64];
  int gcol = blockIdx.x * 64;
  int b = gcol >> 11;
  int l = (gcol & 2047) + (threadIdx.x & 63);
  int w = threadIdx.x >> 6;
  const float* xp = x + ((size_t)b * Cn + w * 64) * Ln + l;
  float acc = 0.f;
  #pragma unroll 8
  for (int cc = 0; cc < 64; ++cc){ float v = xp[(size_t)cc * Ln]; acc += v * v; }
  ps[w][threadIdx.x & 63] = acc;
  __syncthreads();
  if (threadIdx.x < 64){
    float t = ps[0][threadIdx.x] + ps[1][threadIdx.x] + ps[2][threadIdx.x] + ps[3][threadIdx.x];
    s[gcol + threadIdx.x] = 16.0f / fmaxf(sqrtf(t), 1e-12f);
  }
}

// ---------------- transpose + scale + g1 + bf16: xT[(b*Ln+l)*Cn + c] ----------------
__global__ __launch_bounds__(256) void k_xt(const float* __restrict__ x,
                                            const float* __restrict__ s,
                                            const float* __restrict__ g1,
                                            unsigned short* __restrict__ xT){
  __shared__ float xs[64][65];
  int b  = blockIdx.z;
  int c0 = blockIdx.y * 64;
  int l0 = blockIdx.x * 64;
  int t  = threadIdx.x;
  int i = t >> 6, j = t & 63;
  const float* xp = x + ((size_t)b * Cn + c0) * Ln + l0;
  #pragma unroll
  for (int it = 0; it < 16; ++it)
    xs[i + it * 4][j] = xp[(size_t)(i + it * 4) * Ln + j];
  __syncthreads();
  int jj = t >> 2, part = t & 3;
  float sc = s[b * Ln + l0 + jj];
  unsigned short* op = xT + ((size_t)(b * Ln + l0 + jj)) * Cn + c0 + part * 16;
  #pragma unroll
  for (int hb = 0; hb < 2; ++hb){
    short8 pack;
    #pragma unroll
    for (int m = 0; m < 8; ++m){
      int c = part * 16 + hb * 8 + m;
      pack[m] = (short)f2bf(xs[c][jj] * sc * g1[c0 + c]);
    }
    *reinterpret_cast<short8*>(op + hb * 8) = pack;
  }
}

// ---------------- QK GEMM, D[l][o] orientation -> q,k in (b,h,l,d) bf16 ----------------
__global__ __launch_bounds__(256) void k_gemm_qk(const unsigned short* __restrict__ xT,
                                                 const unsigned short* __restrict__ w,
                                                 unsigned short* __restrict__ qb,
                                                 unsigned short* __restrict__ kb){
  int b  = blockIdx.z;
  int l0 = blockIdx.x * 128;
  int n0 = blockIdx.y * 64;
  int wv = threadIdx.x >> 6, lane = threadIdx.x & 63;
  int grp = lane >> 4, lc = lane & 15;
  int lw = l0 + (wv >> 1) * 64;
  int nw = n0 + (wv & 1) * 32;
  f32x4 acc[4][2] = {};
  const unsigned short* xb = xT + (size_t)b * Ln * Cn;
  for (int k0 = 0; k0 < Cn; k0 += 32){
    int kc = k0 + grp * 8;
    short8 afr[4], bfr[2];
    #pragma unroll
    for (int mt = 0; mt < 4; ++mt)
      afr[mt] = *reinterpret_cast<const short8*>(xb + (size_t)(lw + mt * 16 + lc) * Cn + kc);
    #pragma unroll
    for (int nt = 0; nt < 2; ++nt)
      bfr[nt] = *reinterpret_cast<const short8*>(w + (size_t)(nw + nt * 16 + lc) * Cn + kc);
    #pragma unroll
    for (int mt = 0; mt < 4; ++mt)
      #pragma unroll
      for (int nt = 0; nt < 2; ++nt)
        acc[mt][nt] = __builtin_amdgcn_mfma_f32_16x16x32_bf16(afr[mt], bfr[nt], acc[mt][nt], 0, 0, 0);
  }
  // q scale folds dim_head^-0.5 AND log2(e) (attn softmax runs in exp2 domain)
  const float QSCALE = 0.125f * 1.4426950408889634f;
  #pragma unroll
  for (int mt = 0; mt < 4; ++mt)
    #pragma unroll
    for (int nt = 0; nt < 2; ++nt)
      #pragma unroll
      for (int r = 0; r < 4; ++r){
        int l = lw + mt * 16 + grp * 4 + r;
        int o = nw + nt * 16 + lc;
        float v = acc[mt][nt][r];
        if (o < HIDn){
          size_t idx = (((size_t)(b * Hn + (o >> 6)) * Ln + l) << 6) | (size_t)(o & 63);
          qb[idx] = f2bf(v * QSCALE);
        } else {
          int o2 = o - HIDn;
          size_t idx = (((size_t)(b * Hn + (o2 >> 6)) * Ln + l) << 6) | (size_t)(o2 & 63);
          kb[idx] = f2bf(v);
        }
      }
}

// ---------------- V GEMM, D[o][l] orientation -> v in (b, 512, l) bf16 ----------------
__global__ __launch_bounds__(256) void k_gemm_v(const unsigned short* __restrict__ xT,
                                                const unsigned short* __restrict__ w,
                                                unsigned short* __restrict__ vb){
  int b  = blockIdx.z;
  int m0 = blockIdx.y * 64;
  int l0 = blockIdx.x * 128;
  int wv = threadIdx.x >> 6, lane = threadIdx.x & 63;
  int grp = lane >> 4, lc = lane & 15;
  int mw = m0 + (wv >> 1) * 32;
  int lw = l0 + (wv & 1) * 64;
  f32x4 acc[2][4] = {};
  const unsigned short* xb = xT + (size_t)b * Ln * Cn;
  const unsigned short* wvp = w + (size_t)1024 * Cn;
  for (int k0 = 0; k0 < Cn; k0 += 32){
    int kc = k0 + grp * 8;
    short8 afr[2], bfr[4];
    #pragma unroll
    for (int mt = 0; mt < 2; ++mt)
      afr[mt] = *reinterpret_cast<const short8*>(wvp + (size_t)(mw + mt * 16 + lc) * Cn + kc);
    #pragma unroll
    for (int nt = 0; nt < 4; ++nt)
      bfr[nt] = *reinterpret_cast<const short8*>(xb + (size_t)(lw + nt * 16 + lc) * Cn + kc);
    #pragma unroll
    for (int mt = 0; mt < 2; ++mt)
      #pragma unroll
      for (int nt = 0; nt < 4; ++nt)
        acc[mt][nt] = __builtin_amdgcn_mfma_f32_16x16x32_bf16(afr[mt], bfr[nt], acc[mt][nt], 0, 0, 0);
  }
  #pragma unroll
  for (int mt = 0; mt < 2; ++mt)
    #pragma unroll
    for (int nt = 0; nt < 4; ++nt)
      #pragma unroll
      for (int r = 0; r < 4; ++r){
        int o = mw + mt * 16 + grp * 4 + r;
        int l = lw + nt * 16 + lc;
        vb[((size_t)(b * HIDn + o)) * Ln + l] = f2bf(acc[mt][nt][r]);
      }
}

// ---------------- flash attention, pipelined swapped-operand structure ----------------
// 512 blocks (XCD-swizzled) x 4 waves; wave owns 32 q-rows; KVBLK=64.
// 4-buffer LDS, DMA issued 3 tiles ahead, counted vmcnt(4) + raw s_barrier (1/tile).
// Iteration t: QK(t+1) on MFMA pipe overlaps SM(t) on VALU; PV(t) follows.
// PV runs in a permuted k-order so sacc registers ARE the B-frags: zero cross-lane
// movement (16 cvt_pk only). V A-frags read the same permuted order via 8B LDS reads.
__global__ __launch_bounds__(256) void k_attn(const unsigned short* __restrict__ qb,
                                              const unsigned short* __restrict__ kb,
                                              const unsigned short* __restrict__ vb,
                                              unsigned short* __restrict__ yb){
  int wid = (blockIdx.x & 7) * 64 + (blockIdx.x >> 3);   // XCD-aware, bijective (512 % 8 == 0)
  int qt = wid & 15;
  int bh = wid >> 4;
  int b = bh >> 3, h = bh & 7;
  int tid = threadIdx.x;
  int wv = tid >> 6, lane = tid & 63;
  int ln = lane & 31, hi = lane >> 5;

  const unsigned short* qp = qb + (size_t)bh * Ln * Dn;
  const unsigned short* kp = kb + (size_t)bh * Ln * Dn;
  const unsigned short* vp = vb + ((size_t)(b * HIDn + h * Dn)) * Ln;
  unsigned short* yp = yb + (size_t)b * Ln * HIDn + h * Dn;

  __shared__ alignas(16) unsigned short KV[4][2][4096];   // [buf][K|V][64 rows x 64], XOR-swizzled content

  // staging: wave wv owns rows [wv*16, wv*16+16), 2 gl16 per operand per tile.
  // LDS dest linear; source pre-swizzled: chunk = lcol ^ (row & 7).
  int lrow = lane >> 3, lcol = lane & 7;
  int chunk = lcol ^ lrow;
  int srow = wv * 16 + lrow;
  const unsigned short* kg = kp + (size_t)srow * Dn + chunk * 8;
  const unsigned short* vg = vp + (size_t)srow * Ln + chunk * 8;
  int ldK = wv * 1024;

  int q = qt * 128 + wv * 32 + ln;
  int sw = (ln & 7) << 4;

  f32x16 accO[2] = {};
  f32x16 sA[2], sB[2];
  float m = -1e30f, lsum = 0.f;
  const f32x16 ZV = {};

  auto DMA = [&](int tile, int buf){
    const unsigned short* kgn = kg + (size_t)tile * 64 * Dn;
    const unsigned short* vgn = vg + (size_t)tile * 64;
    unsigned short* Kd = &KV[buf][0][ldK];
    unsigned short* Vd = &KV[buf][1][ldK];
    gl16(kgn,          Kd);
    gl16(kgn + 8 * Dn, Kd + 512);
    gl16(vgn,          Vd);
    gl16(vgn + 8 * Ln, Vd + 512);
  };

  // prologue
  DMA(0, 0);
  DMA(1, 1);
  short8 qf[4];
  #pragma unroll
  for (int s = 0; s < 4; ++s)
    qf[s] = *reinterpret_cast<const short8*>(qp + (size_t)q * Dn + s * 16 + hi * 8);
  asm volatile("s_waitcnt vmcnt(4)" ::: "memory");   // tiles 0,1 landed (qf still out)
  __builtin_amdgcn_s_barrier();
  DMA(2, 2);

  // first QK (tile 0) -> sA
  {
    const char* Kc = (const char*)&KV[0][0][0];
    sA[0] = ZV; sA[1] = ZV;
    #pragma unroll
    for (int kb2 = 0; kb2 < 2; ++kb2){
      const char* Kr = Kc + (kb2 * 32 + ln) * 128;
      #pragma unroll
      for (int s = 0; s < 4; ++s){
        short8 kf = *reinterpret_cast<const short8*>(Kr + ((s * 32 + hi * 16) ^ sw));
        sA[kb2] = __builtin_amdgcn_mfma_f32_32x32x16_bf16(kf, qf[s], sA[kb2], 0, 0, 0);
      }
    }
  }

  auto ITER = [&](int t, f32x16 (&sC)[2], f32x16 (&sN)[2]){
    // ---- issue DMA 3 ahead (clamped; clobbers tile t-1's buffer, barrier-safe)
    int tl = t + 3; if (tl > 31) tl = 31;
    DMA(tl, (t + 3) & 3);

    // ---- QK(t+1) -> sN (MFMA pipe; overlaps SM below)
    if (t + 1 < 32){
      const char* Kc = (const char*)&KV[(t + 1) & 3][0][0];
      sN[0] = ZV; sN[1] = ZV;
      __builtin_amdgcn_s_setprio(1);
      #pragma unroll
      for (int kb2 = 0; kb2 < 2; ++kb2){
        const char* Kr = Kc + (kb2 * 32 + ln) * 128;
        #pragma unroll
        for (int s = 0; s < 4; ++s){
          short8 kf = *reinterpret_cast<const short8*>(Kr + ((s * 32 + hi * 16) ^ sw));
          sN[kb2] = __builtin_amdgcn_mfma_f32_32x32x16_bf16(kf, qf[s], sN[kb2], 0, 0, 0);
        }
      }
      __builtin_amdgcn_s_setprio(0);
    }

    // ---- SM(t) on sC (VALU)
    float mx[8];
    #pragma unroll
    for (int r = 0; r < 8; ++r)
      mx[r] = fmaxf(fmaxf(sC[0][r], sC[0][r + 8]), fmaxf(sC[1][r], sC[1][r + 8]));
    float pl = fmax3(fmax3(mx[0], mx[1], mx[2]),
                     fmax3(mx[3], mx[4], mx[5]),
                     fmaxf(mx[6], mx[7]));
    float pmax = fmaxf(pl, __shfl_xor(pl, 32, 64));

    if (!__all(pmax - m <= 8.0f)){                     // defer-max rescale (rare)
      float mn = fmaxf(m, pmax);
      float corr = exp2f(m - mn);
      lsum *= corr;
      #pragma unroll
      for (int db = 0; db < 2; ++db)
        #pragma unroll
        for (int r = 0; r < 16; ++r) accO[db][r] *= corr;
      m = mn;
    }

    float s0[16];
    #pragma unroll
    for (int r = 0; r < 16; ++r){
      float p0, p1;
      asm("v_exp_f32 %0, %1" : "=v"(p0) : "v"(sC[0][r] - m));
      asm("v_exp_f32 %0, %1" : "=v"(p1) : "v"(sC[1][r] - m));
      sC[0][r] = p0; sC[1][r] = p1;
      s0[r] = p0 + p1;
    }
    #pragma unroll
    for (int st = 8; st >= 1; st >>= 1)
      #pragma unroll
      for (int r = 0; r < st; ++r) s0[r] += s0[r + st];
    lsum += s0[0] + __shfl_xor(s0[0], 32, 64);

    // ---- PV(t): permuted-k contraction; sacc regs ARE the B-frags
    const char* Vc = (const char*)&KV[t & 3][1][0];
    __builtin_amdgcn_s_setprio(1);
    #pragma unroll
    for (int c = 0; c < 4; ++c){
      int base = (c & 1) * 8, kb2 = c >> 1;
      u32x4 W;
      W[0] = cvtpk(sC[kb2][base + 0], sC[kb2][base + 1]);
      W[1] = cvtpk(sC[kb2][base + 2], sC[kb2][base + 3]);
      W[2] = cvtpk(sC[kb2][base + 4], sC[kb2][base + 5]);
      W[3] = cvtpk(sC[kb2][base + 6], sC[kb2][base + 7]);
      short8 Bf = __builtin_bit_cast(short8, W);
      #pragma unroll
      for (int db = 0; db < 2; ++db){
        const char* Vr = Vc + (db * 32 + ln) * 128;
        s16x4 a0 = *reinterpret_cast<const s16x4*>(Vr + ((c * 32) ^ sw) + hi * 8);
        s16x4 a1 = *reinterpret_cast<const s16x4*>(Vr + ((c * 32 + 16) ^ sw) + hi * 8);
        short8 Af = {a0[0], a0[1], a0[2], a0[3], a1[0], a1[1], a1[2], a1[3]};
        accO[db] = __builtin_amdgcn_mfma_f32_32x32x16_bf16(Af, Bf, accO[db], 0, 0, 0);
      }
    }
    __builtin_amdgcn_s_setprio(0);

    // ---- single sync point: own t+2 loads landed, everyone done reading b[t]
    asm volatile("s_waitcnt vmcnt(4)" ::: "memory");
    __builtin_amdgcn_s_barrier();
  };

  for (int t = 0; t < 32; t += 2){
    ITER(t,     sA, sB);
    ITER(t + 1, sB, sA);
  }

  // ---- epilogue: O^T[d][q] / lsum -> y[(b,l,512)]
  float inv = 1.0f / lsum;
  #pragma unroll
  for (int db = 0; db < 2; ++db)
    #pragma unroll
    for (int rq = 0; rq < 4; ++rq){
      uint32_t w0 = cvtpk(accO[db][rq * 4 + 0] * inv, accO[db][rq * 4 + 1] * inv);
      uint32_t w1 = cvtpk(accO[db][rq * 4 + 2] * inv, accO[db][rq * 4 + 3] * inv);
      int dd = db * 32 + rq * 8 + hi * 4;
      uint32_t* dst = reinterpret_cast<uint32_t*>(yp + (size_t)q * HIDn + dd);
      dst[0] = w0; dst[1] = w1;
    }
}

// ---------------- out GEMM (M=256 full) + bias + fused RMSNorm + g2 ----------------
__global__ __launch_bounds__(256) void k_out(const unsigned short* __restrict__ yb,
                                             const unsigned short* __restrict__ w,
                                             const float* __restrict__ bias,
                                             const float* __restrict__ g2,
                                             float* __restrict__ out){
  int b  = blockIdx.y;
  int l0 = blockIdx.x * 32;
  int wv = threadIdx.x >> 6, lane = threadIdx.x & 63;
  int grp = lane >> 4, lc = lane & 15;
  int mw = wv * 64;
  f32x4 acc[4][2] = {};
  const unsigned short* ybp = yb + (size_t)b * Ln * HIDn + (size_t)l0 * HIDn;
  for (int k0 = 0; k0 < HIDn; k0 += 32){
    int kc = k0 + grp * 8;
    short8 afr[4], bfr[2];
    #pragma unroll
    for (int mt = 0; mt < 4; ++mt)
      afr[mt] = *reinterpret_cast<const short8*>(w + (size_t)(mw + mt * 16 + lc) * HIDn + kc);
    #pragma unroll
    for (int nt = 0; nt < 2; ++nt)
      bfr[nt] = *reinterpret_cast<const short8*>(ybp + (size_t)(nt * 16 + lc) * HIDn + kc);
    #pragma unroll
    for (int mt = 0; mt < 4; ++mt)
      #pragma unroll
      for (int nt = 0; nt < 2; ++nt)
        acc[mt][nt] = __builtin_amdgcn_mfma_f32_16x16x32_bf16(afr[mt], bfr[nt], acc[mt][nt], 0, 0, 0);
  }
  __shared__ float cs[4][32];
  __shared__ float sc2[32];
  float part[2] = {0.f, 0.f};
  #pragma unroll
  for (int mt = 0; mt < 4; ++mt)
    #pragma unroll
    for (int nt = 0; nt < 2; ++nt)
      #pragma unroll
      for (int r = 0; r < 4; ++r){
        int o = mw + mt * 16 + grp * 4 + r;
        float v = acc[mt][nt][r] + bias[o];
        acc[mt][nt][r] = v;
        part[nt] += v * v;
      }
  #pragma unroll
  for (int nt = 0; nt < 2; ++nt)
    #pragma unroll
    for (int sh = 16; sh < 64; sh <<= 1) part[nt] += __shfl_xor(part[nt], sh, 64);
  if (lane < 16){ cs[wv][lc] = part[0]; cs[wv][16 + lc] = part[1]; }
  __syncthreads();
  if (threadIdx.x < 32){
    float t = cs[0][threadIdx.x] + cs[1][threadIdx.x] + cs[2][threadIdx.x] + cs[3][threadIdx.x];
    sc2[threadIdx.x] = 16.0f / fmaxf(sqrtf(t), 1e-12f);
  }
  __syncthreads();
  #pragma unroll
  for (int nt = 0; nt < 2; ++nt){
    float s2 = sc2[nt * 16 + lc];
    #pragma unroll
    for (int mt = 0; mt < 4; ++mt)
      #pragma unroll
      for (int r = 0; r < 4; ++r){
        int o = mw + mt * 16 + grp * 4 + r;
        int l = l0 + nt * 16 + lc;
        out[((size_t)(b * Cn + o)) * Ln + l] = acc[mt][nt][r] * s2 * g2[o];
      }
  }
}

// ---------------- launch ----------------
extern "C" void kernel_launch(void* const* d_in, const int* in_sizes, int n_in,
                              void* d_out, int out_size, void* d_ws, size_t ws_size,
                              hipStream_t stream){
  const float* x     = (const float*)d_in[0];
  const float* g1    = (const float*)d_in[1];
  const float* w_qkv = (const float*)d_in[2];
  const float* w_out = (const float*)d_in[3];
  const float* b_out = (const float*)d_in[4];
  const float* g2    = (const float*)d_in[5];

  char* wsb = (char*)d_ws;
  unsigned short* wqkv_b = (unsigned short*)(wsb + 0);
  unsigned short* wout_b = (unsigned short*)(wsb + 786432);
  float*          sbuf   = (float*)        (wsb + 1048576);
  unsigned short* xT     = (unsigned short*)(wsb + 1081344);
  unsigned short* qbuf   = (unsigned short*)(wsb + 5275648);
  unsigned short* kbuf   = (unsigned short*)(wsb + 13664256);
  unsigned short* vbuf   = (unsigned short*)(wsb + 22052864);
  unsigned short* ybuf   = (unsigned short*)(wsb + 30441472);

  k_cvt<<<384, 256, 0, stream>>>(w_qkv, wqkv_b, 1536 * 256);
  k_cvt<<<128, 256, 0, stream>>>(w_out, wout_b, 256 * 512);
  k_colnorm<<<128, 256, 0, stream>>>(x, sbuf);
  k_xt<<<dim3(32, 4, 4), 256, 0, stream>>>(x, sbuf, g1, xT);
  k_gemm_qk<<<dim3(16, 16, 4), 256, 0, stream>>>(xT, wqkv_b, qbuf, kbuf);
  k_gemm_v<<<dim3(16, 8, 4), 256, 0, stream>>>(xT, wqkv_b, vbuf);
  k_attn<<<512, 256, 0, stream>>>(qbuf, kbuf, vbuf, ybuf);
  k_out<<<dim3(64, 4), 256, 0, stream>>>(ybuf, wout_b, b_out, g2, (float*)d_out);
}

// Round 7
// 126.597 us; speedup vs baseline: 1.2256x; 1.0468x over previous
//
#include <hip/hip_runtime.h>
#include <cstdint>
#include <cstddef>

using s16x4  = __attribute__((ext_vector_type(4))) short;   // 4 bf16 (2 VGPRs)
using short8 = __attribute__((ext_vector_type(8))) short;   // 8 bf16 (4 VGPRs)
using f32x4  = __attribute__((ext_vector_type(4))) float;   // MFMA C/D 16x16
using f32x16 = __attribute__((ext_vector_type(16))) float;  // MFMA C/D 32x32
using u32x4  = __attribute__((ext_vector_type(4))) unsigned int;

#define DEV static __device__ __forceinline__

constexpr int Bn = 4, Cn = 256, Ln = 2048, Hn = 8, Dn = 64, HIDn = 512;

DEV unsigned short f2bf(float f){            // fp32 -> bf16 bits, round-nearest-even
  union { float f; uint32_t u; } v; v.f = f;
  uint32_t u = v.u;
  return (unsigned short)((u + 0x7FFFu + ((u >> 16) & 1u)) >> 16);
}

DEV uint32_t cvtpk(float lo, float hi){      // pack 2 f32 -> 2 bf16 (lo -> bits[15:0])
  uint32_t r;
  asm("v_cvt_pk_bf16_f32 %0, %1, %2" : "=v"(r) : "v"(lo), "v"(hi));
  return r;
}

DEV float fmax3(float a, float b, float c){ return fmaxf(fmaxf(a, b), c); }  // fuses to v_max3_f32

// async global -> LDS, 16B per lane, linear dest (wave-uniform base + lane*16)
DEV void gl16(const unsigned short* g, unsigned short* l){
  __builtin_amdgcn_global_load_lds((const __attribute__((address_space(1))) void*)g,
                                   (__attribute__((address_space(3))) void*)l, 16, 0, 0);
}

// ---------------- fused prep: colnorm (blocks 0..127) + w_qkv cvt (128..511) + w_out cvt (512..639)
__global__ __launch_bounds__(256) void k_prep(const float* __restrict__ x,
                                              float* __restrict__ s,
                                              const float* __restrict__ wqkv,
                                              unsigned short* __restrict__ wqkv_b,
                                              const float* __restrict__ wout,
                                              unsigned short* __restrict__ wout_b){
  __shared__ float ps[4][64];
  int bid = blockIdx.x;
  int tid = threadIdx.x;
  if (bid < 128){
    int gcol = bid * 64;
    int b = gcol >> 11;
    int l = (gcol & 2047) + (tid & 63);
    int w = tid >> 6;
    const float* xp = x + ((size_t)b * Cn + w * 64) * Ln + l;
    float acc = 0.f;
    #pragma unroll 8
    for (int cc = 0; cc < 64; ++cc){ float v = xp[(size_t)cc * Ln]; acc += v * v; }
    ps[w][tid & 63] = acc;
    __syncthreads();
    if (tid < 64){
      float t = ps[0][tid] + ps[1][tid] + ps[2][tid] + ps[3][tid];
      s[gcol + tid] = 16.0f / fmaxf(sqrtf(t), 1e-12f);
    }
  } else if (bid < 512){
    int idx = (bid - 128) * 256 + tid;
    #pragma unroll
    for (int it = 0; it < 4; ++it){ wqkv_b[idx] = f2bf(wqkv[idx]); idx += 98304; }
  } else {
    int idx = (bid - 512) * 256 + tid;
    #pragma unroll
    for (int it = 0; it < 4; ++it){ wout_b[idx] = f2bf(wout[idx]); idx += 32768; }
  }
}

// ---------------- transpose + scale + g1 + bf16: xT[(b*Ln+l)*Cn + c] ----------------
__global__ __launch_bounds__(256) void k_xt(const float* __restrict__ x,
                                            const float* __restrict__ s,
                                            const float* __restrict__ g1,
                                            unsigned short* __restrict__ xT){
  __shared__ float xs[64][65];
  int b  = blockIdx.z;
  int c0 = blockIdx.y * 64;
  int l0 = blockIdx.x * 64;
  int t  = threadIdx.x;
  int i = t >> 6, j = t & 63;
  const float* xp = x + ((size_t)b * Cn + c0) * Ln + l0;
  #pragma unroll
  for (int it = 0; it < 16; ++it)
    xs[i + it * 4][j] = xp[(size_t)(i + it * 4) * Ln + j];
  __syncthreads();
  int jj = t >> 2, part = t & 3;
  float sc = s[b * Ln + l0 + jj];
  unsigned short* op = xT + ((size_t)(b * Ln + l0 + jj)) * Cn + c0 + part * 16;
  #pragma unroll
  for (int hb = 0; hb < 2; ++hb){
    short8 pack;
    #pragma unroll
    for (int m = 0; m < 8; ++m){
      int c = part * 16 + hb * 8 + m;
      pack[m] = (short)f2bf(xs[c][jj] * sc * g1[c0 + c]);
    }
    *reinterpret_cast<short8*>(op + hb * 8) = pack;
  }
}

// ---------------- merged QKV GEMM ----------------
// blockIdx.y < 16: QK path (D[l][o] -> q,k in (b,h,l,d));  y in 16..23: V path (D[o][l] -> v (b,512,l))
__global__ __launch_bounds__(256) void k_gemm_qkv(const unsigned short* __restrict__ xT,
                                                  const unsigned short* __restrict__ w,
                                                  unsigned short* __restrict__ qb,
                                                  unsigned short* __restrict__ kb,
                                                  unsigned short* __restrict__ vb){
  int b  = blockIdx.z;
  int l0 = blockIdx.x * 128;
  int wv = threadIdx.x >> 6, lane = threadIdx.x & 63;
  int grp = lane >> 4, lc = lane & 15;
  const unsigned short* xb = xT + (size_t)b * Ln * Cn;
  if (blockIdx.y < 16){
    int n0 = blockIdx.y * 64;
    int lw = l0 + (wv >> 1) * 64;
    int nw = n0 + (wv & 1) * 32;
    f32x4 acc[4][2] = {};
    for (int k0 = 0; k0 < Cn; k0 += 32){
      int kc = k0 + grp * 8;
      short8 afr[4], bfr[2];
      #pragma unroll
      for (int mt = 0; mt < 4; ++mt)
        afr[mt] = *reinterpret_cast<const short8*>(xb + (size_t)(lw + mt * 16 + lc) * Cn + kc);
      #pragma unroll
      for (int nt = 0; nt < 2; ++nt)
        bfr[nt] = *reinterpret_cast<const short8*>(w + (size_t)(nw + nt * 16 + lc) * Cn + kc);
      #pragma unroll
      for (int mt = 0; mt < 4; ++mt)
        #pragma unroll
        for (int nt = 0; nt < 2; ++nt)
          acc[mt][nt] = __builtin_amdgcn_mfma_f32_16x16x32_bf16(afr[mt], bfr[nt], acc[mt][nt], 0, 0, 0);
    }
    const float QSCALE = 0.125f * 1.4426950408889634f;   // fold d^-0.5 and log2(e)
    #pragma unroll
    for (int mt = 0; mt < 4; ++mt)
      #pragma unroll
      for (int nt = 0; nt < 2; ++nt)
        #pragma unroll
        for (int r = 0; r < 4; ++r){
          int l = lw + mt * 16 + grp * 4 + r;
          int o = nw + nt * 16 + lc;
          float v = acc[mt][nt][r];
          if (o < HIDn){
            size_t idx = (((size_t)(b * Hn + (o >> 6)) * Ln + l) << 6) | (size_t)(o & 63);
            qb[idx] = f2bf(v * QSCALE);
          } else {
            int o2 = o - HIDn;
            size_t idx = (((size_t)(b * Hn + (o2 >> 6)) * Ln + l) << 6) | (size_t)(o2 & 63);
            kb[idx] = f2bf(v);
          }
        }
  } else {
    int m0 = (blockIdx.y - 16) * 64;
    int mw = m0 + (wv >> 1) * 32;
    int lw = l0 + (wv & 1) * 64;
    f32x4 acc[2][4] = {};
    const unsigned short* wvp = w + (size_t)1024 * Cn;
    for (int k0 = 0; k0 < Cn; k0 += 32){
      int kc = k0 + grp * 8;
      short8 afr[2], bfr[4];
      #pragma unroll
      for (int mt = 0; mt < 2; ++mt)
        afr[mt] = *reinterpret_cast<const short8*>(wvp + (size_t)(mw + mt * 16 + lc) * Cn + kc);
      #pragma unroll
      for (int nt = 0; nt < 4; ++nt)
        bfr[nt] = *reinterpret_cast<const short8*>(xb + (size_t)(lw + nt * 16 + lc) * Cn + kc);
      #pragma unroll
      for (int mt = 0; mt < 2; ++mt)
        #pragma unroll
        for (int nt = 0; nt < 4; ++nt)
          acc[mt][nt] = __builtin_amdgcn_mfma_f32_16x16x32_bf16(afr[mt], bfr[nt], acc[mt][nt], 0, 0, 0);
    }
    #pragma unroll
    for (int mt = 0; mt < 2; ++mt)
      #pragma unroll
      for (int nt = 0; nt < 4; ++nt)
        #pragma unroll
        for (int r = 0; r < 4; ++r){
          int o = mw + mt * 16 + grp * 4 + r;
          int l = lw + nt * 16 + lc;
          vb[((size_t)(b * HIDn + o)) * Ln + l] = f2bf(acc[mt][nt][r]);
        }
  }
}

// ---------------- flash attention, split-KV 8-wave blocks ----------------
// 512 blocks (XCD-swizzled) x 8 waves (512 thr). Waves 0-3: KV half 0, waves 4-7: half 1;
// wave (half, wsub) computes q-subtile wsub (32 rows) over its 16 KV tiles.
// 2-buffer LDS per half (64KB total); DMA next tile, compute, vmcnt(0)+barrier (latency
// hidden under compute). After the loop, online-softmax merge of the two halves in LDS.
// 4096 waves total -> 4 waves/SIMD (was 2): TLP hides the QK->SM->PV serial chain.
__global__ __launch_bounds__(512) void k_attn(const unsigned short* __restrict__ qb,
                                              const unsigned short* __restrict__ kb,
                                              const unsigned short* __restrict__ vb,
                                              unsigned short* __restrict__ yb){
  int bid = blockIdx.x;
  int wid = (bid & 7) * 64 + (bid >> 3);     // XCD-aware, bijective (512 % 8 == 0)
  int qt = wid & 15;
  int bh = wid >> 4;
  int b = bh >> 3, h = bh & 7;
  int tid = threadIdx.x;
  int wv = tid >> 6, lane = tid & 63;
  int half = wv >> 2, wsub = wv & 3;
  int ln = lane & 31, hi = lane >> 5;

  const unsigned short* qp = qb + (size_t)bh * Ln * Dn;
  const unsigned short* kp = kb + (size_t)bh * Ln * Dn;
  const unsigned short* vp = vb + ((size_t)(b * HIDn + h * Dn)) * Ln;
  unsigned short* yp = yb + (size_t)b * Ln * HIDn + h * Dn;

  __shared__ alignas(16) unsigned short KV2[2][2][2][4096];  // [half][buf][K|V][64x64], swizzled

  // staging: wave stages rows [wsub*16, wsub*16+16) of its half's tile.
  int lrow = lane >> 3, lcol = lane & 7;
  int chunk = lcol ^ lrow;                    // content swizzle: slot = col ^ (row&7)
  int srow = wsub * 16 + lrow;
  const unsigned short* kg = kp + ((size_t)half * 1024 + srow) * Dn + chunk * 8;
  const unsigned short* vg = vp + (size_t)srow * Ln + half * 1024 + chunk * 8;
  int ldK = wsub * 1024;

  int q = qt * 128 + wsub * 32 + ln;
  int sw = (ln & 7) << 4;

  auto DMA = [&](int t, int buf){
    unsigned short* Kd = &KV2[half][buf][0][ldK];
    unsigned short* Vd = &KV2[half][buf][1][ldK];
    const unsigned short* kgn = kg + (size_t)t * 64 * Dn;
    const unsigned short* vgn = vg + (size_t)t * 64;
    gl16(kgn,          Kd);
    gl16(kgn + 8 * Dn, Kd + 512);
    gl16(vgn,          Vd);
    gl16(vgn + 8 * Ln, Vd + 512);
  };

  f32x16 accO[2] = {};
  float m = -1e30f, lsum = 0.f;
  const f32x16 ZV = {};

  // prologue
  DMA(0, 0);
  short8 qf[4];
  #pragma unroll
  for (int s = 0; s < 4; ++s)
    qf[s] = *reinterpret_cast<const short8*>(qp + (size_t)q * Dn + s * 16 + hi * 8);
  asm volatile("s_waitcnt vmcnt(0)" ::: "memory");
  __builtin_amdgcn_s_barrier();

  for (int t = 0; t < 16; ++t){
    if (t + 1 < 16) DMA(t + 1, (t + 1) & 1);

    const char* Kc = (const char*)&KV2[half][t & 1][0][0];
    const char* Vc = (const char*)&KV2[half][t & 1][1][0];

    // ---- S^T = K Q^T
    f32x16 sacc[2];
    sacc[0] = ZV; sacc[1] = ZV;
    __builtin_amdgcn_s_setprio(1);
    #pragma unroll
    for (int kb2 = 0; kb2 < 2; ++kb2){
      const char* Kr = Kc + (kb2 * 32 + ln) * 128;
      #pragma unroll
      for (int s = 0; s < 4; ++s){
        short8 kf = *reinterpret_cast<const short8*>(Kr + ((s * 32 + hi * 16) ^ sw));
        sacc[kb2] = __builtin_amdgcn_mfma_f32_32x32x16_bf16(kf, qf[s], sacc[kb2], 0, 0, 0);
      }
    }
    __builtin_amdgcn_s_setprio(0);

    // ---- softmax (lane-local; 2 cross-half shfls)
    float mx[8];
    #pragma unroll
    for (int r = 0; r < 8; ++r)
      mx[r] = fmaxf(fmaxf(sacc[0][r], sacc[0][r + 8]), fmaxf(sacc[1][r], sacc[1][r + 8]));
    float pl = fmax3(fmax3(mx[0], mx[1], mx[2]),
                     fmax3(mx[3], mx[4], mx[5]),
                     fmaxf(mx[6], mx[7]));
    float pmax = fmaxf(pl, __shfl_xor(pl, 32, 64));

    if (!__all(pmax - m <= 8.0f)){                     // defer-max rescale (rare)
      float mn = fmaxf(m, pmax);
      float corr = exp2f(m - mn);
      lsum *= corr;
      #pragma unroll
      for (int db = 0; db < 2; ++db)
        #pragma unroll
        for (int r = 0; r < 16; ++r) accO[db][r] *= corr;
      m = mn;
    }

    float s0[16];
    #pragma unroll
    for (int r = 0; r < 16; ++r){
      float p0, p1;
      asm("v_exp_f32 %0, %1" : "=v"(p0) : "v"(sacc[0][r] - m));
      asm("v_exp_f32 %0, %1" : "=v"(p1) : "v"(sacc[1][r] - m));
      sacc[0][r] = p0; sacc[1][r] = p1;
      s0[r] = p0 + p1;
    }
    #pragma unroll
    for (int st = 8; st >= 1; st >>= 1)
      #pragma unroll
      for (int r = 0; r < st; ++r) s0[r] += s0[r + st];
    lsum += s0[0] + __shfl_xor(s0[0], 32, 64);

    // ---- PV: permuted-k contraction; sacc regs ARE the B-frags (no cross-lane moves)
    __builtin_amdgcn_s_setprio(1);
    #pragma unroll
    for (int c = 0; c < 4; ++c){
      int base = (c & 1) * 8, kb2 = c >> 1;
      u32x4 W;
      W[0] = cvtpk(sacc[kb2][base + 0], sacc[kb2][base + 1]);
      W[1] = cvtpk(sacc[kb2][base + 2], sacc[kb2][base + 3]);
      W[2] = cvtpk(sacc[kb2][base + 4], sacc[kb2][base + 5]);
      W[3] = cvtpk(sacc[kb2][base + 6], sacc[kb2][base + 7]);
      short8 Bf = __builtin_bit_cast(short8, W);
      #pragma unroll
      for (int db = 0; db < 2; ++db){
        const char* Vr = Vc + (db * 32 + ln) * 128;
        s16x4 a0 = *reinterpret_cast<const s16x4*>(Vr + ((c * 32) ^ sw) + hi * 8);
        s16x4 a1 = *reinterpret_cast<const s16x4*>(Vr + ((c * 32 + 16) ^ sw) + hi * 8);
        short8 Af = {a0[0], a0[1], a0[2], a0[3], a1[0], a1[1], a1[2], a1[3]};
        accO[db] = __builtin_amdgcn_mfma_f32_32x32x16_bf16(Af, Bf, accO[db], 0, 0, 0);
      }
    }
    __builtin_amdgcn_s_setprio(0);

    // ---- next tile landed; all waves done reading buf t&1
    asm volatile("s_waitcnt vmcnt(0)" ::: "memory");
    __builtin_amdgcn_s_barrier();
  }

  // ---- merge the two KV halves (online-softmax combine), then write y
  float* mo = (float*)&KV2[0][0][0][0];      // reuse: [wsub][8][64][4] f32 accO + m/lsum at +8192
  __syncthreads();
  if (half == 1){
    #pragma unroll
    for (int r4 = 0; r4 < 8; ++r4){
      int db = r4 >> 2, rq = r4 & 3;
      f32x4 vv = { accO[db][rq * 4 + 0], accO[db][rq * 4 + 1],
                   accO[db][rq * 4 + 2], accO[db][rq * 4 + 3] };
      *reinterpret_cast<f32x4*>(&mo[wsub * 2048 + r4 * 256 + lane * 4]) = vv;
    }
    if (hi == 0){
      mo[8192 + wsub * 64 + ln * 2 + 0] = m;
      mo[8192 + wsub * 64 + ln * 2 + 1] = lsum;
    }
  }
  __syncthreads();
  if (half == 0){
    float m1 = mo[8192 + wsub * 64 + ln * 2 + 0];
    float l1 = mo[8192 + wsub * 64 + ln * 2 + 1];
    float mn = fmaxf(m, m1);
    float c0 = exp2f(m - mn);
    float c1 = exp2f(m1 - mn);
    float inv = 1.0f / (lsum * c0 + l1 * c1);
    #pragma unroll
    for (int r4 = 0; r4 < 8; ++r4){
      int db = r4 >> 2, rq = r4 & 3;
      f32x4 o1 = *reinterpret_cast<const f32x4*>(&mo[wsub * 2048 + r4 * 256 + lane * 4]);
      float v0 = (accO[db][rq * 4 + 0] * c0 + o1[0] * c1) * inv;
      float v1 = (accO[db][rq * 4 + 1] * c0 + o1[1] * c1) * inv;
      float v2 = (accO[db][rq * 4 + 2] * c0 + o1[2] * c1) * inv;
      float v3 = (accO[db][rq * 4 + 3] * c0 + o1[3] * c1) * inv;
      uint32_t w0 = cvtpk(v0, v1);
      uint32_t w1 = cvtpk(v2, v3);
      int dd = db * 32 + rq * 8 + hi * 4;
      uint32_t* dst = reinterpret_cast<uint32_t*>(yp + (size_t)q * HIDn + dd);
      dst[0] = w0; dst[1] = w1;
    }
  }
}

// ---------------- out GEMM (M=256 full) + bias + fused RMSNorm + g2 ----------------
__global__ __launch_bounds__(256) void k_out(const unsigned short* __restrict__ yb,
                                             const unsigned short* __restrict__ w,
                                             const float* __restrict__ bias,
                                             const float* __restrict__ g2,
                                             float* __restrict__ out){
  int b  = blockIdx.y;
  int l0 = blockIdx.x * 32;
  int wv = threadIdx.x >> 6, lane = threadIdx.x & 63;
  int grp = lane >> 4, lc = lane & 15;
  int mw = wv * 64;
  f32x4 acc[4][2] = {};
  const unsigned short* ybp = yb + (size_t)b * Ln * HIDn + (size_t)l0 * HIDn;
  for (int k0 = 0; k0 < HIDn; k0 += 32){
    int kc = k0 + grp * 8;
    short8 afr[4], bfr[2];
    #pragma unroll
    for (int mt = 0; mt < 4; ++mt)
      afr[mt] = *reinterpret_cast<const short8*>(w + (size_t)(mw + mt * 16 + lc) * HIDn + kc);
    #pragma unroll
    for (int nt = 0; nt < 2; ++nt)
      bfr[nt] = *reinterpret_cast<const short8*>(ybp + (size_t)(nt * 16 + lc) * HIDn + kc);
    #pragma unroll
    for (int mt = 0; mt < 4; ++mt)
      #pragma unroll
      for (int nt = 0; nt < 2; ++nt)
        acc[mt][nt] = __builtin_amdgcn_mfma_f32_16x16x32_bf16(afr[mt], bfr[nt], acc[mt][nt], 0, 0, 0);
  }
  __shared__ float cs[4][32];
  __shared__ float sc2[32];
  float part[2] = {0.f, 0.f};
  #pragma unroll
  for (int mt = 0; mt < 4; ++mt)
    #pragma unroll
    for (int nt = 0; nt < 2; ++nt)
      #pragma unroll
      for (int r = 0; r < 4; ++r){
        int o = mw + mt * 16 + grp * 4 + r;
        float v = acc[mt][nt][r] + bias[o];
        acc[mt][nt][r] = v;
        part[nt] += v * v;
      }
  #pragma unroll
  for (int nt = 0; nt < 2; ++nt)
    #pragma unroll
    for (int sh = 16; sh < 64; sh <<= 1) part[nt] += __shfl_xor(part[nt], sh, 64);
  if (lane < 16){ cs[wv][lc] = part[0]; cs[wv][16 + lc] = part[1]; }
  __syncthreads();
  if (threadIdx.x < 32){
    float t = cs[0][threadIdx.x] + cs[1][threadIdx.x] + cs[2][threadIdx.x] + cs[3][threadIdx.x];
    sc2[threadIdx.x] = 16.0f / fmaxf(sqrtf(t), 1e-12f);
  }
  __syncthreads();
  #pragma unroll
  for (int nt = 0; nt < 2; ++nt){
    float s2 = sc2[nt * 16 + lc];
    #pragma unroll
    for (int mt = 0; mt < 4; ++mt)
      #pragma unroll
      for (int r = 0; r < 4; ++r){
        int o = mw + mt * 16 + grp * 4 + r;
        int l = l0 + nt * 16 + lc;
        out[((size_t)(b * Cn + o)) * Ln + l] = acc[mt][nt][r] * s2 * g2[o];
      }
  }
}

// ---------------- launch ----------------
extern "C" void kernel_launch(void* const* d_in, const int* in_sizes, int n_in,
                              void* d_out, int out_size, void* d_ws, size_t ws_size,
                              hipStream_t stream){
  const float* x     = (const float*)d_in[0];
  const float* g1    = (const float*)d_in[1];
  const float* w_qkv = (const float*)d_in[2];
  const float* w_out = (const float*)d_in[3];
  const float* b_out = (const float*)d_in[4];
  const float* g2    = (const float*)d_in[5];

  char* wsb = (char*)d_ws;
  unsigned short* wqkv_b = (unsigned short*)(wsb + 0);
  unsigned short* wout_b = (unsigned short*)(wsb + 786432);
  float*          sbuf   = (float*)        (wsb + 1048576);
  unsigned short* xT     = (unsigned short*)(wsb + 1081344);
  unsigned short* qbuf   = (unsigned short*)(wsb + 5275648);
  unsigned short* kbuf   = (unsigned short*)(wsb + 13664256);
  unsigned short* vbuf   = (unsigned short*)(wsb + 22052864);
  unsigned short* ybuf   = (unsigned short*)(wsb + 30441472);

  k_prep<<<640, 256, 0, stream>>>(x, sbuf, w_qkv, wqkv_b, w_out, wout_b);
  k_xt<<<dim3(32, 4, 4), 256, 0, stream>>>(x, sbuf, g1, xT);
  k_gemm_qkv<<<dim3(16, 24, 4), 256, 0, stream>>>(xT, wqkv_b, qbuf, kbuf, vbuf);
  k_attn<<<512, 512, 0, stream>>>(qbuf, kbuf, vbuf, ybuf);
  k_out<<<dim3(64, 4), 256, 0, stream>>>(ybuf, wout_b, b_out, g2, (float*)d_out);
}